// Round 4
// baseline (190.550 us; speedup 1.0000x reference)
//
#include <hip/hip_runtime.h>
#include <cstdint>

// ViT patch embedding, two-stage, fragment-direct GEMM (no LDS, no barriers):
//   prep_patch: images fp32 -> A in MFMA-FRAGMENT order: [m16][k32][lane][8] bf16
//   prep_small: W fp32 -> B fragment order [n16][k32][lane][8]; cls rows -> out
//   vit_gemm4:  each wave = 64x128 tile, loads frags straight from global
//               (global_load_dwordx4, base+lane*16 coalesced), 1-step prefetch,
//               zero LDS / zero __syncthreads. R3 was phase-serialized on the
//               LDS round-trip + barriers; this removes both.

#define PGRID 14
#define PSZ   16
#define CHN   3
#define IMGW  224
#define KDIM  768
#define NDIM  768
#define NPATCH 196
#define K32   24          // KDIM / 32

typedef short bf16x8 __attribute__((ext_vector_type(8)));
typedef short short8v __attribute__((ext_vector_type(8)));
typedef float f32x4  __attribute__((ext_vector_type(4)));

__device__ __forceinline__ short bf16rne(float f) {
    uint32_t u = __builtin_bit_cast(uint32_t, f);
    u += 0x7FFFu + ((u >> 16) & 1u);
    return (short)(u >> 16);
}

__device__ __forceinline__ short8v cvt8(float4 v0, float4 v1) {
    short8v s;
    s[0] = bf16rne(v0.x); s[1] = bf16rne(v0.y); s[2] = bf16rne(v0.z); s[3] = bf16rne(v0.w);
    s[4] = bf16rne(v1.x); s[5] = bf16rne(v1.y); s[6] = bf16rne(v1.z); s[7] = bf16rne(v1.w);
    return s;
}

// ---------------- prep: patchify + fp32->bf16 into A-fragment layout ----------------
// A_frag[(m16*24 + k32)*512 + lane*8 + j] = A[m16*16 + (lane&15)][k32*32 + (lane>>4)*8 + j]
__global__ __launch_bounds__(256) void prep_patch(
    const float* __restrict__ img, short* __restrict__ A, int M)
{
    int t = blockIdx.x * 256 + threadIdx.x;
    if (t >= M * 96) return;
    int m  = t / 96;
    int k8 = t - m * 96;
    int k  = k8 * 8;
    int c  = k >> 8;
    int ph = (k >> 4) & 15;
    int pw = k & 15;          // 0 or 8 (8 contiguous pixels within one patch row)
    int im = m / NPATCH;
    int p  = m - im * NPATCH;
    int Pi = p / PGRID;
    int Pj = p - Pi * PGRID;
    const float* src = img + (((long)(im * CHN + c) * IMGW + Pi * PSZ + ph) * IMGW + Pj * PSZ + pw);
    float4 v0 = *(const float4*)src;
    float4 v1 = *(const float4*)(src + 4);
    int m16  = m >> 4;
    int k32  = k8 >> 2;
    int quad = k8 & 3;
    int lane = (m & 15) | (quad << 4);
    *(short8v*)(A + (((long)m16 * K32 + k32) << 9) + lane * 8) = cvt8(v0, v1);
}

// ---------------- prep: W -> B-fragment layout + cls fill ----------------
__global__ __launch_bounds__(256) void prep_small(
    const float* __restrict__ Wl, const float* __restrict__ cls,
    short* __restrict__ Wb, float* __restrict__ out, int n_img)
{
    int t = blockIdx.x * 256 + threadIdx.x;
    const int WCH = KDIM * NDIM / 8;   // 73728
    if (t < WCH) {
        int n  = t / 96;
        int k8 = t - n * 96;
        float4 v0 = *(const float4*)(Wl + (long)n * KDIM + k8 * 8);
        float4 v1 = *(const float4*)(Wl + (long)n * KDIM + k8 * 8 + 4);
        int n16  = n >> 4;
        int k32  = k8 >> 2;
        int quad = k8 & 3;
        int lane = (n & 15) | (quad << 4);
        *(short8v*)(Wb + (((long)n16 * K32 + k32) << 9) + lane * 8) = cvt8(v0, v1);
    } else {
        int u = t - WCH;
        if (u < n_img * 96) {
            int im = u / 96;
            int k8 = u - im * 96;
            float4 v0 = *(const float4*)(cls + k8 * 8);
            float4 v1 = *(const float4*)(cls + k8 * 8 + 4);
            float* dst = out + (long)im * 197 * NDIM + k8 * 8;
            *(float4*)dst = v0;
            *(float4*)(dst + 4) = v1;
        }
    }
}

// ---------------- main GEMM: fragment-direct, no LDS ----------------
__global__ __launch_bounds__(256, 2) void vit_gemm4(
    const short* __restrict__ A, const short* __restrict__ B,
    const float* __restrict__ bias, float* __restrict__ out,
    int M, int mgroups)
{
    // XCD swizzle: all 6 n-slices of one m-group on the same XCD (FETCH 33 MB in R3)
    const int bid = blockIdx.x;
    const int xcd = bid & 7;
    const int s   = bid >> 3;
    const int gq  = s / 6;
    const int j   = s - gq * 6;
    const int g   = gq * 8 + xcd;
    if (g >= mgroups) return;
    const int m0 = g * 256;          // block covers 256 m rows (4 waves x 64)
    const int n0 = j * 128;          // and 128 n cols

    const int tid  = threadIdx.x;
    const int wave = tid >> 6;
    const int lane = tid & 63;
    const int wq   = lane >> 4;
    const int lr   = lane & 15;

    // fragment base pointers: +lane*8 shorts -> load = base + lane*16B, coalesced 1KB/instr
    const short* Ab = A + (((long)((m0 >> 4) + wave * 4) * K32) << 9) + lane * 8;
    const short* Bb = B + (((long)(n0 >> 4) * K32) << 9) + lane * 8;
    const long fstride = (long)K32 << 9;   // 12288 shorts per 16-row block

    f32x4 acc[4][8] = {};
    bf16x8 a0[4], b0[8], a1[4], b1[8];

#define LDA(dst, kk) { _Pragma("unroll") for (int i = 0; i < 4; ++i) \
        dst[i] = *(const bf16x8*)(Ab + i * fstride + ((kk) << 9)); }
#define LDB(dst, kk) { _Pragma("unroll") for (int i = 0; i < 8; ++i) \
        dst[i] = *(const bf16x8*)(Bb + i * fstride + ((kk) << 9)); }
#define MM(aa, bb) { _Pragma("unroll") for (int i = 0; i < 4; ++i) \
        _Pragma("unroll") for (int q = 0; q < 8; ++q) \
        acc[i][q] = __builtin_amdgcn_mfma_f32_16x16x32_bf16(aa[i], bb[q], acc[i][q], 0, 0, 0); }

    LDA(a0, 0); LDB(b0, 0);
    for (int k = 0; k < K32; k += 2) {
        LDA(a1, k + 1); LDB(b1, k + 1);
        MM(a0, b0);
        if (k + 2 < K32) { LDA(a0, k + 2); LDB(b0, k + 2); }
        MM(a1, b1);
    }
#undef LDA
#undef LDB
#undef MM

    float bv[8];
    #pragma unroll
    for (int q = 0; q < 8; ++q) bv[q] = bias[n0 + q * 16 + lr];

    const int mw = m0 + wave * 64;
    #pragma unroll
    for (int i = 0; i < 4; ++i) {
        #pragma unroll
        for (int r = 0; r < 4; ++r) {
            int gm = mw + i * 16 + wq * 4 + r;
            if (gm < M) {
                int im = gm / NPATCH;
                int p  = gm - im * NPATCH;
                float* orow = out + ((long)im * 197 + 1 + p) * NDIM + n0 + lr;
                #pragma unroll
                for (int q = 0; q < 8; ++q)
                    orow[q * 16] = acc[i][q][r] + bv[q];
            }
        }
    }
}

// ---------------- fallback (round-1 fused kernel) ----------------
#define LDSTR 40
__global__ __launch_bounds__(256) void vit_gemm_fb(
    const float* __restrict__ img, const float* __restrict__ Wl,
    const float* __restrict__ bias, float* __restrict__ out, int n_img)
{
    const int M = n_img * NPATCH;
    __shared__ short As[128 * LDSTR];
    __shared__ short Bs[128 * LDSTR];
    const int tid = threadIdx.x;
    const int m0 = blockIdx.y * 128;
    const int n0 = blockIdx.x * 128;
    const int col4  = tid & 7;
    const int rbase = tid >> 3;
    long arow[4];
    for (int rr = 0; rr < 4; ++rr) {
        int m = m0 + rbase + rr * 32;
        int mm = (m < M) ? m : (M - 1);
        int im = mm / NPATCH;
        int p  = mm % NPATCH;
        int Pi = p / PGRID;
        int Pj = p % PGRID;
        arow[rr] = ((long)(im * CHN) * IMGW + Pi * PSZ) * IMGW + Pj * PSZ;
    }
    const int lane = tid & 63;
    const int wave = tid >> 6;
    const int wm = (wave & 1) * 64;
    const int wn = (wave >> 1) * 64;
    const int wq = lane >> 4;
    const int lr = lane & 15;
    f32x4 acc[4][4] = {};
    for (int k0 = 0; k0 < KDIM; k0 += 32) {
        {
            int k  = k0 + col4 * 4;
            int c  = k >> 8;
            int ph = (k >> 4) & 15;
            int pw = k & 15;
            long koff = (long)(c * IMGW + ph) * IMGW + pw;
            #pragma unroll
            for (int rr = 0; rr < 4; ++rr) {
                const float4 v = *(const float4*)(img + arow[rr] + koff);
                int row = rbase + rr * 32;
                short4 s;
                s.x = bf16rne(v.x); s.y = bf16rne(v.y);
                s.z = bf16rne(v.z); s.w = bf16rne(v.w);
                *(short4*)(&As[row * LDSTR + col4 * 4]) = s;
            }
        }
        {
            int k = k0 + col4 * 4;
            #pragma unroll
            for (int rr = 0; rr < 4; ++rr) {
                int nrow = rbase + rr * 32;
                const float4 v = *(const float4*)(Wl + (long)(n0 + nrow) * KDIM + k);
                short4 s;
                s.x = bf16rne(v.x); s.y = bf16rne(v.y);
                s.z = bf16rne(v.z); s.w = bf16rne(v.w);
                *(short4*)(&Bs[nrow * LDSTR + col4 * 4]) = s;
            }
        }
        __syncthreads();
        bf16x8 a[4], b[4];
        #pragma unroll
        for (int i = 0; i < 4; ++i)
            a[i] = *(const bf16x8*)(&As[(wm + i * 16 + lr) * LDSTR + wq * 8]);
        #pragma unroll
        for (int i = 0; i < 4; ++i)
            b[i] = *(const bf16x8*)(&Bs[(wn + i * 16 + lr) * LDSTR + wq * 8]);
        #pragma unroll
        for (int i = 0; i < 4; ++i)
            #pragma unroll
            for (int j = 0; j < 4; ++j)
                acc[i][j] = __builtin_amdgcn_mfma_f32_16x16x32_bf16(a[i], b[j], acc[i][j], 0, 0, 0);
        __syncthreads();
    }
    float bv[4];
    #pragma unroll
    for (int j = 0; j < 4; ++j) bv[j] = bias[n0 + wn + j * 16 + lr];
    #pragma unroll
    for (int i = 0; i < 4; ++i) {
        #pragma unroll
        for (int r = 0; r < 4; ++r) {
            int gm = m0 + wm + i * 16 + wq * 4 + r;
            if (gm < M) {
                int im = gm / NPATCH;
                int p  = gm % NPATCH;
                long orow = ((long)im * 197 + 1 + p) * (long)NDIM;
                #pragma unroll
                for (int j = 0; j < 4; ++j)
                    out[orow + n0 + wn + j * 16 + lr] = acc[i][j][r] + bv[j];
            }
        }
    }
}

__global__ __launch_bounds__(256) void cls_fill(
    const float* __restrict__ cls, float* __restrict__ out, int n_img)
{
    int i = blockIdx.x * 256 + threadIdx.x;
    if (i < n_img * NDIM) {
        int im = i / NDIM;
        int n  = i - im * NDIM;
        out[(long)im * 197 * NDIM + n] = cls[n];
    }
}

extern "C" void kernel_launch(void* const* d_in, const int* in_sizes, int n_in,
                              void* d_out, int out_size, void* d_ws, size_t ws_size,
                              hipStream_t stream) {
    const float* img  = (const float*)d_in[0];
    const float* Wl   = (const float*)d_in[1];
    const float* bias = (const float*)d_in[2];
    const float* cls  = (const float*)d_in[3];
    float* out = (float*)d_out;

    int n_img = in_sizes[0] / (CHN * IMGW * IMGW);
    int M = n_img * NPATCH;
    int mgroups = (M + 255) / 256;          // 256-row m-groups
    long Mpad = (long)mgroups * 256;

    size_t need = (size_t)(Mpad * KDIM + (long)KDIM * NDIM) * sizeof(short);
    if (ws_size >= need) {
        short* A_ws = (short*)d_ws;
        short* Wb   = A_ws + Mpad * KDIM;

        prep_patch<<<(M * 96 + 255) / 256, 256, 0, stream>>>(img, A_ws, M);
        int small_total = KDIM * NDIM / 8 + n_img * 96;
        prep_small<<<(small_total + 255) / 256, 256, 0, stream>>>(Wl, cls, Wb, out, n_img);

        int gpad = (mgroups + 7) & ~7;
        int nblocks = gpad * 6;
        vit_gemm4<<<nblocks, 256, 0, stream>>>(A_ws, Wb, bias, out, M, mgroups);
    } else {
        int mb = (M + 127) / 128;
        dim3 grid(NDIM / 128, mb);
        vit_gemm_fb<<<grid, 256, 0, stream>>>(img, Wl, bias, out, n_img);
        int cls_elems = n_img * NDIM;
        cls_fill<<<(cls_elems + 255) / 256, 256, 0, stream>>>(cls, out, n_img);
    }
}